// Round 9
// baseline (55.527 us; speedup 1.0000x reference)
//
#include <hip/hip_runtime.h>

// B=4096 tokens, NB=16 branches, S=256 hidden, D=1024.
// out = x + ( relu(x) @ W_in[y]^T + b_in[y] ) @ W_out[y]^T + b_out[y]
// Grouped-GEMM, 4 dispatches. R8 skeleton (K-split gemm1, 1280-block occupancy fix)
// + R9 change: prep casts W_in only; W_out cast is a grid-stride tail of gemm1
// (24 MB hidden under gemm1's vmcnt stalls at 20 waves/CU — R7's idea, which
// failed only at 320-block occupancy).
//  K1 prep:   block 0 = setup; blocks 1..2048 cast W_in -> bf16
//  K2 gemm1:  grid (4,80,4) = 1280 blocks; 64x64 tile, 4 K-steps over a 256-K
//             chunk, 2-phase dbuf, f32 partials to Hpart[4][.][.]; then Wo-cast tail
//  K3 reduce: Hp = bf16( sum_ks Hpart + b_in )  (640 blocks, streaming)
//  K4 gemm2:  64x64 tiles -> 1280 blocks, K=256, 2-phase dbuf,
//             LDS-bounce coalesced epilogue with bias + residual scatter
// Publishing contract: EXPLICIT `s_waitcnt vmcnt(0)` before any barrier that
// publishes a global_load_lds-staged buffer (R3 lesson).
// LDS bank conflicts: XOR swizzle; gload_lds tiles use linear LDS dest +
// pre-swizzled per-lane global source (m173); reg-staged A writes swizzled.
// dur_us model: ~40us fixed harness ws-poison + our kernels (~15us) — optimize
// only the kernel portion.

typedef unsigned short u16;
typedef short bf16x8 __attribute__((ext_vector_type(8)));
typedef float f32x4 __attribute__((ext_vector_type(4)));

#define MFMA16 __builtin_amdgcn_mfma_f32_16x16x32_bf16

constexpr int B_TOK = 4096;
constexpr int NB = 16;
constexpr int S_DIM = 256;
constexpr int D_DIM = 1024;
constexpr int BM = 64;
constexpr int PAD_ROWS = B_TOK + NB * BM;    // 5120
constexpr int NTILES = PAD_ROWS / BM;        // 80
constexpr int KSPLIT = 4;                    // gemm1 K-chunks (1024/4 = 256)
constexpr int HP_ELEMS = PAD_ROWS * S_DIM;   // 1310720 per k-chunk
constexpr int W_ITEMS = NB * S_DIM * D_DIM / 8;   // 524288 cast items (8 f32 each)

__device__ __forceinline__ unsigned short f2bf(float f) {
    unsigned u = __builtin_bit_cast(unsigned, f);
    u += 0x7fffu + ((u >> 16) & 1u);   // RNE
    return (unsigned short)(u >> 16);
}
__device__ __forceinline__ unsigned pack2(float a, float b) {
    return (unsigned)f2bf(a) | ((unsigned)f2bf(b) << 16);
}
__device__ __forceinline__ void gload_lds16(const void* g, void* l) {
    __builtin_amdgcn_global_load_lds(
        (const __attribute__((address_space(1))) void*)g,
        (__attribute__((address_space(3))) void*)l, 16, 0, 0);
}
// Publish staged LDS: drain all vmem (incl. global_load_lds), then barrier.
__device__ __forceinline__ void publish() {
    asm volatile("s_waitcnt vmcnt(0)" ::: "memory");
    __syncthreads();
}
// fp32 -> bf16, 8 elems per item j
__device__ __forceinline__ void cast8(const float* __restrict__ src,
                                      u16* __restrict__ dst, int j) {
    const float4* p = (const float4*)src + (size_t)j * 2;
    float4 v0 = p[0], v1 = p[1];
    uint4 o;
    o.x = pack2(v0.x, v0.y);
    o.y = pack2(v0.z, v0.w);
    o.z = pack2(v1.x, v1.y);
    o.w = pack2(v1.z, v1.w);
    ((uint4*)dst)[j] = o;
}

// ---------------------------------------------------------------------------
// K1: setup (block 0) + W_in cast (blocks 1..2048)
// ---------------------------------------------------------------------------
__global__ __launch_bounds__(256) void prep_kernel(
    const float* __restrict__ Wi_f, u16* __restrict__ Wi,
    const int* __restrict__ y, int* __restrict__ perm, int* __restrict__ tileBranch) {
    const int t = threadIdx.x;
    if (blockIdx.x == 0) {
        __shared__ int hist[NB];
        __shared__ int aoff[NB + 1];
        __shared__ int cursor[NB];
        if (t < NB) hist[t] = 0;
        __syncthreads();
        for (int i = t; i < B_TOK; i += 256) atomicAdd(&hist[y[i]], 1);
        __syncthreads();
        if (t == 0) {
            int off = 0;
            for (int n = 0; n < NB; ++n) {
                aoff[n] = off;
                cursor[n] = off;
                off += ((hist[n] + BM - 1) / BM) * BM;
            }
            aoff[NB] = off;
        }
        __syncthreads();
        for (int i = t; i < NTILES; i += 256) {
            int rb = i * BM, br = -1;
            for (int n = 0; n < NB; ++n)
                if (rb >= aoff[n] && rb < aoff[n + 1]) br = n;
            tileBranch[i] = br;
        }
        for (int i = t; i < PAD_ROWS; i += 256) perm[i] = -1;
        __syncthreads();
        for (int i = t; i < B_TOK; i += 256) {
            int pos = atomicAdd(&cursor[y[i]], 1);
            perm[pos] = i;
        }
        return;
    }
    cast8(Wi_f, Wi, (blockIdx.x - 1) * 256 + t);   // 2048*256 == W_ITEMS exactly
}

// ---------------------------------------------------------------------------
// K2: GEMM1 partials.  Hpart[ks][5120p,256] = relu(x[perm]) @ W_in[br]^T
// grid (4 col, 80 row, 4 kchunk) = 1280 blocks. 64x64 tile, BK=64, 4 K-steps.
// A reg-staged (x gather + relu + cvt, swizzled ds_write); B via gload_lds.
// Tail: grid-stride cast of W_out -> bf16 (consumed only by gemm2).
// ---------------------------------------------------------------------------
__global__ __launch_bounds__(256) void gemm1_kernel(
    const float* __restrict__ x, const u16* __restrict__ Wi,
    const int* __restrict__ tileBranch, const int* __restrict__ perm,
    float* __restrict__ Hpart,
    const float* __restrict__ Wo_f, u16* __restrict__ Wo) {
    const int branch = tileBranch[blockIdx.y];
    const int t = threadIdx.x;

    if (branch >= 0) {
        const int rowBase = blockIdx.y * BM;
        const int colBase = blockIdx.x * 64;
        const int kbase = blockIdx.z * (D_DIM / KSPLIT);   // 0,256,512,768

        __shared__ u16 sA[2][64 * 64];   // 8 KB each, XOR-swizzled
        __shared__ u16 sB[2][64 * 64];

        // A staging map: 4 threads/row, 16 floats each
        const int sr = t >> 2;
        const int scg = t & 3;
        const int tok = perm[rowBase + sr];
        const float* aSrc = (tok >= 0) ? (x + (size_t)tok * D_DIM + scg * 16) : x;
        const int sbyte0 = (sr * 128 + scg * 32) ^ ((sr & 7) << 4);
        const int sbyte1 = sbyte0 ^ 16;

        const u16* Bb = Wi + (size_t)branch * S_DIM * D_DIM + (size_t)colBase * D_DIM;

        const int lane = t & 63;
        const int wid = t >> 6;
        const int wm = (wid >> 1) * 32;
        const int wn = (wid & 1) * 32;
        const int fr = lane & 15;
        const int kc = (lane >> 4) << 3;

        f32x4 acc[2][2] = {};
        float4 av0, av1, av2, av3;

        auto loadA = [&](int k0) {
            const float4* pa = (const float4*)(aSrc + k0);
            av0 = pa[0]; av1 = pa[1]; av2 = pa[2]; av3 = pa[3];
        };
        auto stageB = [&](int buf, int k0) {
#pragma unroll
            for (int i = 0; i < 2; ++i) {
                const int L = i * 4096 + t * 16;
                const int row = L >> 7;
                const int sunit = ((L >> 4) & 7) ^ (row & 7);
                gload_lds16((const char*)Bb + (size_t)row * (D_DIM * 2) + k0 * 2 + sunit * 16,
                            (char*)sB[buf] + L);
            }
        };
        auto packWriteA = [&](int buf) {
            uint4 w0, w1;
            if (tok >= 0) {
                w0.x = pack2(fmaxf(av0.x, 0.f), fmaxf(av0.y, 0.f));
                w0.y = pack2(fmaxf(av0.z, 0.f), fmaxf(av0.w, 0.f));
                w0.z = pack2(fmaxf(av1.x, 0.f), fmaxf(av1.y, 0.f));
                w0.w = pack2(fmaxf(av1.z, 0.f), fmaxf(av1.w, 0.f));
                w1.x = pack2(fmaxf(av2.x, 0.f), fmaxf(av2.y, 0.f));
                w1.y = pack2(fmaxf(av2.z, 0.f), fmaxf(av2.w, 0.f));
                w1.z = pack2(fmaxf(av3.x, 0.f), fmaxf(av3.y, 0.f));
                w1.w = pack2(fmaxf(av3.z, 0.f), fmaxf(av3.w, 0.f));
            } else {
                w0 = make_uint4(0, 0, 0, 0);
                w1 = make_uint4(0, 0, 0, 0);
            }
            *(uint4*)((char*)sA[buf] + sbyte0) = w0;
            *(uint4*)((char*)sA[buf] + sbyte1) = w1;
        };

        loadA(kbase);
        stageB(0, kbase);
        packWriteA(0);
        publish();

        for (int kt = 0; kt < 4; ++kt) {
            const int cur = kt & 1;
            if (kt < 3) {
                const int k0n = kbase + ((kt + 1) << 6);
                stageB(cur ^ 1, k0n);
                loadA(k0n);
            }
#pragma unroll
            for (int kk = 0; kk < 2; ++kk) {
                const int kcol = kc + kk * 32;
                const int ra0 = wm + fr, ra1 = wm + 16 + fr;
                const int rb0 = wn + fr, rb1 = wn + 16 + fr;
                bf16x8 a0 = *(const bf16x8*)&sA[cur][(ra0 * 64 + kcol) ^ ((ra0 & 7) << 3)];
                bf16x8 a1 = *(const bf16x8*)&sA[cur][(ra1 * 64 + kcol) ^ ((ra1 & 7) << 3)];
                bf16x8 b0 = *(const bf16x8*)&sB[cur][(rb0 * 64 + kcol) ^ ((rb0 & 7) << 3)];
                bf16x8 b1 = *(const bf16x8*)&sB[cur][(rb1 * 64 + kcol) ^ ((rb1 & 7) << 3)];
                acc[0][0] = MFMA16(a0, b0, acc[0][0], 0, 0, 0);
                acc[0][1] = MFMA16(a0, b1, acc[0][1], 0, 0, 0);
                acc[1][0] = MFMA16(a1, b0, acc[1][0], 0, 0, 0);
                acc[1][1] = MFMA16(a1, b1, acc[1][1], 0, 0, 0);
            }
            if (kt < 3) packWriteA(cur ^ 1);
            publish();   // vmcnt(0) drains stage(kt+1), then barrier publishes
        }

        float* Op = Hpart + (size_t)blockIdx.z * HP_ELEMS;
        const int r0 = (lane >> 4) * 4;
#pragma unroll
        for (int m = 0; m < 2; ++m) {
            const int prow0 = rowBase + wm + m * 16 + r0;
#pragma unroll
            for (int n = 0; n < 2; ++n) {
                const int col = colBase + wn + n * 16 + fr;
#pragma unroll
                for (int r = 0; r < 4; ++r)
                    Op[(size_t)(prow0 + r) * S_DIM + col] = acc[m][n][r];
            }
        }
    }

    // ---- tail: cast W_out -> bf16, grid-strided over all 1280 blocks.
    // Consumed only by gemm2 (next dispatch) — hides under gemm1 vmcnt stalls.
    const int bid = (blockIdx.z * NTILES + blockIdx.y) * 4 + blockIdx.x;
    for (int j = bid * 256 + t; j < W_ITEMS; j += 4 * NTILES * KSPLIT * 256)
        cast8(Wo_f, Wo, j);
}

// ---------------------------------------------------------------------------
// K3: reduce — Hp[row,col] = bf16( sum_ks Hpart[ks][row,col] + b_in[br][col] )
// 640 blocks x 256 thr, 8 cols per thread.
// ---------------------------------------------------------------------------
__global__ __launch_bounds__(256) void reduce_kernel(
    const float* __restrict__ Hpart, const float* __restrict__ b_in,
    const int* __restrict__ tileBranch, u16* __restrict__ Hp) {
    const int j = blockIdx.x * 256 + threadIdx.x;   // 0 .. 163839
    const int row = j >> 5;
    const int c8 = (j & 31) << 3;
    const int branch = tileBranch[row >> 6];
    if (branch < 0) return;
    const float* p = Hpart + (size_t)row * S_DIM + c8;
    float4 s0 = *(const float4*)p;
    float4 s1 = *(const float4*)(p + 4);
#pragma unroll
    for (int ks = 1; ks < KSPLIT; ++ks) {
        const float* q = p + (size_t)ks * HP_ELEMS;
        float4 a0 = *(const float4*)q;
        float4 a1 = *(const float4*)(q + 4);
        s0.x += a0.x; s0.y += a0.y; s0.z += a0.z; s0.w += a0.w;
        s1.x += a1.x; s1.y += a1.y; s1.z += a1.z; s1.w += a1.w;
    }
    const float* bp = b_in + (size_t)branch * S_DIM + c8;
    float4 b0 = *(const float4*)bp;
    float4 b1 = *(const float4*)(bp + 4);
    uint4 o;
    o.x = pack2(s0.x + b0.x, s0.y + b0.y);
    o.y = pack2(s0.z + b0.z, s0.w + b0.w);
    o.z = pack2(s1.x + b1.x, s1.y + b1.y);
    o.w = pack2(s1.z + b1.z, s1.w + b1.w);
    *(uint4*)&Hp[(size_t)row * S_DIM + c8] = o;
}

// ---------------------------------------------------------------------------
// K4: GEMM2  out[tok,1024] = x[tok] + Hp @ W_out[br]^T + b_out
// 64x64 tiles -> grid (16, 80) = 1280 blocks. K=256 (4 steps), 2-phase dbuf,
// both operands via gload_lds, LDS-bounce coalesced epilogue.
// ---------------------------------------------------------------------------
__global__ __launch_bounds__(256) void gemm2_kernel(
    const u16* __restrict__ Hp, const u16* __restrict__ Wo,
    const float* __restrict__ b_out, const int* __restrict__ tileBranch,
    const int* __restrict__ perm, const float* __restrict__ x,
    float* __restrict__ out) {
    const int branch = tileBranch[blockIdx.y];
    if (branch < 0) return;
    const int rowBase = blockIdx.y * BM;
    const int colBase = blockIdx.x * 64;

    __shared__ __align__(16) char smem[32768];  // sA[2]8K | sB[2]8K ; bounce 17.4K overlay
    u16* sA0 = (u16*)smem;
    u16* sA1 = (u16*)(smem + 8192);
    u16* sB0 = (u16*)(smem + 16384);
    u16* sB1 = (u16*)(smem + 24576);

    const int t = threadIdx.x;
    const u16* Ab = Hp + (size_t)rowBase * S_DIM;
    const u16* Bb = Wo + (size_t)branch * D_DIM * S_DIM + (size_t)colBase * S_DIM;

    const int lane = t & 63;
    const int wid = t >> 6;
    const int wm = (wid >> 1) * 32;
    const int wn = (wid & 1) * 32;
    const int fr = lane & 15;
    const int kc = (lane >> 4) << 3;

    f32x4 acc[2][2] = {};

    auto stage = [&](u16* dA, u16* dB, int k0) {
#pragma unroll
        for (int i = 0; i < 2; ++i) {
            const int L = i * 4096 + t * 16;
            const int row = L >> 7;
            const int sunit = ((L >> 4) & 7) ^ (row & 7);
            gload_lds16((const char*)Ab + (size_t)row * (S_DIM * 2) + k0 * 2 + sunit * 16,
                        (char*)dA + L);
        }
#pragma unroll
        for (int i = 0; i < 2; ++i) {
            const int L = i * 4096 + t * 16;
            const int row = L >> 7;
            const int sunit = ((L >> 4) & 7) ^ (row & 7);
            gload_lds16((const char*)Bb + (size_t)row * (S_DIM * 2) + k0 * 2 + sunit * 16,
                        (char*)dB + L);
        }
    };
    auto compute = [&](const u16* cA, const u16* cB) {
#pragma unroll
        for (int kk = 0; kk < 2; ++kk) {
            const int kcol = kc + kk * 32;
            const int ra0 = wm + fr, ra1 = wm + 16 + fr;
            const int rb0 = wn + fr, rb1 = wn + 16 + fr;
            bf16x8 a0 = *(const bf16x8*)&cA[(ra0 * 64 + kcol) ^ ((ra0 & 7) << 3)];
            bf16x8 a1 = *(const bf16x8*)&cA[(ra1 * 64 + kcol) ^ ((ra1 & 7) << 3)];
            bf16x8 b0 = *(const bf16x8*)&cB[(rb0 * 64 + kcol) ^ ((rb0 & 7) << 3)];
            bf16x8 b1 = *(const bf16x8*)&cB[(rb1 * 64 + kcol) ^ ((rb1 & 7) << 3)];
            acc[0][0] = MFMA16(a0, b0, acc[0][0], 0, 0, 0);
            acc[0][1] = MFMA16(a0, b1, acc[0][1], 0, 0, 0);
            acc[1][0] = MFMA16(a1, b0, acc[1][0], 0, 0, 0);
            acc[1][1] = MFMA16(a1, b1, acc[1][1], 0, 0, 0);
        }
    };

    stage(sA0, sB0, 0);
    publish();
#pragma unroll
    for (int kt = 0; kt < 4; ++kt) {
        const bool even = (kt & 1) == 0;
        u16* cA = even ? sA0 : sA1;
        u16* cB = even ? sB0 : sB1;
        u16* nA = even ? sA1 : sA0;
        u16* nB = even ? sB1 : sB0;
        if (kt < 3) stage(nA, nB, (kt + 1) << 6);
        compute(cA, cB);
        publish();   // vmcnt(0) drains gload_lds (had the MFMA phase to land) + barrier
    }

    // ---- LDS-bounce epilogue: acc -> smem[64][68] f32 -> coalesced stores
    float* bo = (float*)smem;
    const int r0 = (lane >> 4) * 4;
#pragma unroll
    for (int m = 0; m < 2; ++m)
#pragma unroll
        for (int n = 0; n < 2; ++n)
#pragma unroll
            for (int r = 0; r < 4; ++r)
                bo[(wm + m * 16 + r0 + r) * 68 + wn + n * 16 + fr] = acc[m][n][r];
    __syncthreads();

    const int erow = t >> 2;                  // 0..63
    const int q4 = (t & 3) * 4;               // f32 col base within 16-col group
    const int tok2 = perm[rowBase + erow];
    if (tok2 >= 0) {
        const size_t gbase = (size_t)tok2 * D_DIM + colBase;
        const float* xr = x + gbase;
        float* orow = out + gbase;
        const float* br = b_out + (size_t)branch * D_DIM + colBase;
#pragma unroll
        for (int j = 0; j < 4; ++j) {
            const int c = q4 + j * 16;        // 4 lanes cover 16 consecutive f32
            float4 xv = *(const float4*)&xr[c];
            float4 bvv = *(const float4*)&br[c];
            float4 hv = *(const float4*)&bo[erow * 68 + c];
            float4 s;
            s.x = xv.x + bvv.x + hv.x;
            s.y = xv.y + bvv.y + hv.y;
            s.z = xv.z + bvv.z + hv.z;
            s.w = xv.w + bvv.w + hv.w;
            *(float4*)&orow[c] = s;
        }
    }
}

// ---------------------------------------------------------------------------
extern "C" void kernel_launch(void* const* d_in, const int* in_sizes, int n_in,
                              void* d_out, int out_size, void* d_ws, size_t ws_size,
                              hipStream_t stream) {
    const float* x     = (const float*)d_in[0];
    const int*   y     = (const int*)d_in[1];
    const float* W_in  = (const float*)d_in[2];
    const float* b_in  = (const float*)d_in[3];
    const float* W_out = (const float*)d_in[4];
    const float* b_out = (const float*)d_in[5];
    float* out = (float*)d_out;

    char* ws = (char*)d_ws;
    u16* Wi = (u16*)(ws);                        // 8 MB
    u16* Wo = (u16*)(ws + 8388608);              // 8 MB
    u16* Hp = (u16*)(ws + 16777216);             // 2.62 MB
    float* Hpart = (float*)(ws + 19398656);      // 4 * 5.24 MB = 20.97 MB
    int* perm = (int*)(ws + 40370176);           // 5120*4
    int* tileBranch = (int*)(ws + 40390656);     // 80*4

    prep_kernel<<<2049, 256, 0, stream>>>(W_in, Wi, y, perm, tileBranch);

    gemm1_kernel<<<dim3(4, NTILES, KSPLIT), 256, 0, stream>>>(
        x, Wi, tileBranch, perm, Hpart, W_out, Wo);

    reduce_kernel<<<640, 256, 0, stream>>>(Hpart, b_in, tileBranch, Hp);

    gemm2_kernel<<<dim3(16, NTILES), 256, 0, stream>>>(
        Hp, Wo, b_out, tileBranch, perm, x, out);
}

// Round 10
// 51.222 us; speedup vs baseline: 1.0840x; 1.0840x over previous
//
#include <hip/hip_runtime.h>

// B=4096 tokens, NB=16 branches, S=256 hidden, D=1024.
// out = x + ( relu(x) @ W_in[y]^T + b_in[y] ) @ W_out[y]^T + b_out[y]
// Grouped-GEMM, 3 dispatches. R10: replace R8's K-split+reduce with 32x64
// gemm1 tiles (640 blocks, full K per block) — drops the 40MB Hpart round-trip,
// the reduce dispatch, and one launch gap. 2.5 blocks/CU hides the 16-step chain
// (R7's stall was at 1.25 blocks/CU).
//  K1 prep:  block 0 = setup; blocks 1..4096 cast W_in+W_out -> bf16
//  K2 gemm1: 32x64 tiles, grid (4,160) = 640 blocks, BK=64 x 16 steps, 2-phase
//            dbuf, A reg-staged (x gather+relu+cvt, swizzled ds_write),
//            B via gload_lds; bias in epilogue, bf16 Hp direct
//  K3 gemm2: 64x64 tiles, grid (16,80) = 1280 blocks, K=256, 2-phase dbuf,
//            both operands gload_lds, LDS-bounce epilogue w/ bias + residual
// Publishing contract: EXPLICIT `s_waitcnt vmcnt(0)` before any barrier that
// publishes a global_load_lds-staged buffer (R3 lesson).
// LDS bank conflicts: XOR swizzle; gload_lds tiles use linear LDS dest +
// pre-swizzled per-lane global source (m173); reg-staged A writes swizzled.
// dur_us model: ~40us invariant harness component + our kernels (~15us).

typedef unsigned short u16;
typedef short bf16x8 __attribute__((ext_vector_type(8)));
typedef float f32x4 __attribute__((ext_vector_type(4)));

#define MFMA16 __builtin_amdgcn_mfma_f32_16x16x32_bf16

constexpr int B_TOK = 4096;
constexpr int NB = 16;
constexpr int S_DIM = 256;
constexpr int D_DIM = 1024;
constexpr int BM = 64;
constexpr int PAD_ROWS = B_TOK + NB * BM;    // 5120
constexpr int NTILES = PAD_ROWS / BM;        // 80 (64-row tiles, gemm2)
constexpr int NTILES32 = PAD_ROWS / 32;      // 160 (32-row tiles, gemm1)

__device__ __forceinline__ unsigned short f2bf(float f) {
    unsigned u = __builtin_bit_cast(unsigned, f);
    u += 0x7fffu + ((u >> 16) & 1u);   // RNE
    return (unsigned short)(u >> 16);
}
__device__ __forceinline__ unsigned pack2(float a, float b) {
    return (unsigned)f2bf(a) | ((unsigned)f2bf(b) << 16);
}
__device__ __forceinline__ void gload_lds16(const void* g, void* l) {
    __builtin_amdgcn_global_load_lds(
        (const __attribute__((address_space(1))) void*)g,
        (__attribute__((address_space(3))) void*)l, 16, 0, 0);
}
// Publish staged LDS: drain all vmem (incl. global_load_lds), then barrier.
__device__ __forceinline__ void publish() {
    asm volatile("s_waitcnt vmcnt(0)" ::: "memory");
    __syncthreads();
}
// fp32 -> bf16, 8 elems per item j
__device__ __forceinline__ void cast8(const float* __restrict__ src,
                                      u16* __restrict__ dst, int j) {
    const float4* p = (const float4*)src + (size_t)j * 2;
    float4 v0 = p[0], v1 = p[1];
    uint4 o;
    o.x = pack2(v0.x, v0.y);
    o.y = pack2(v0.z, v0.w);
    o.z = pack2(v1.x, v1.y);
    o.w = pack2(v1.z, v1.w);
    ((uint4*)dst)[j] = o;
}

// ---------------------------------------------------------------------------
// K1: setup (block 0) + W casts (blocks 1..4096)
// ---------------------------------------------------------------------------
__global__ __launch_bounds__(256) void prep_kernel(
    const float* __restrict__ Wi_f, const float* __restrict__ Wo_f,
    u16* __restrict__ Wi, u16* __restrict__ Wo,
    const int* __restrict__ y, int* __restrict__ perm, int* __restrict__ tileBranch) {
    const int t = threadIdx.x;
    if (blockIdx.x == 0) {
        __shared__ int hist[NB];
        __shared__ int aoff[NB + 1];
        __shared__ int cursor[NB];
        if (t < NB) hist[t] = 0;
        __syncthreads();
        for (int i = t; i < B_TOK; i += 256) atomicAdd(&hist[y[i]], 1);
        __syncthreads();
        if (t == 0) {
            int off = 0;
            for (int n = 0; n < NB; ++n) {
                aoff[n] = off;
                cursor[n] = off;
                off += ((hist[n] + BM - 1) / BM) * BM;
            }
            aoff[NB] = off;
        }
        __syncthreads();
        for (int i = t; i < NTILES; i += 256) {
            int rb = i * BM, br = -1;
            for (int n = 0; n < NB; ++n)
                if (rb >= aoff[n] && rb < aoff[n + 1]) br = n;
            tileBranch[i] = br;
        }
        for (int i = t; i < PAD_ROWS; i += 256) perm[i] = -1;
        __syncthreads();
        for (int i = t; i < B_TOK; i += 256) {
            int pos = atomicAdd(&cursor[y[i]], 1);
            perm[pos] = i;
        }
        return;
    }
    int i = (blockIdx.x - 1) * 256 + t;          // 0 .. 1048575
    if (i < 524288) cast8(Wi_f, Wi, i);
    else            cast8(Wo_f, Wo, i - 524288);
}

// ---------------------------------------------------------------------------
// K2: GEMM1  Hp[5120p,256] = bf16( relu(x[perm]) @ W_in[br]^T + b_in )
// 32x64 tiles, grid (4 col, 160 row) = 640 blocks. BK=64, 16 K-steps, 2-phase
// dbuf. 256 thr = 4 waves in 2x2 (wave tile 16x32). A reg-staged, B gload_lds.
// ---------------------------------------------------------------------------
__global__ __launch_bounds__(256) void gemm1_kernel(
    const float* __restrict__ x, const u16* __restrict__ Wi,
    const float* __restrict__ b_in, const int* __restrict__ tileBranch,
    const int* __restrict__ perm, u16* __restrict__ Hp) {
    const int branch = tileBranch[blockIdx.y >> 1];   // 64-aligned segments
    if (branch < 0) return;
    const int rowBase = blockIdx.y * 32;
    const int colBase = blockIdx.x * 64;
    const int t = threadIdx.x;

    __shared__ u16 sA[2][32 * 64];   // 4 KB each, XOR-swizzled
    __shared__ u16 sB[2][64 * 64];   // 8 KB each, swizzled via pre-swizzled source

    // A staging: 8 threads/row, 8 floats each
    const int sr = t >> 3;           // 0..31
    const int scg = t & 7;           // 8-float col group
    const int tok = perm[rowBase + sr];
    const float* aSrc = (tok >= 0) ? (x + (size_t)tok * D_DIM + scg * 8) : x;
    const int sbyte = (sr * 128 + scg * 16) ^ ((sr & 7) << 4);

    const u16* Bb = Wi + (size_t)branch * S_DIM * D_DIM + (size_t)colBase * D_DIM;

    const int lane = t & 63;
    const int wid = t >> 6;
    const int wm = (wid >> 1) * 16;  // wave row offset (0/16)
    const int wn = (wid & 1) * 32;   // wave col offset (0/32)
    const int fr = lane & 15;
    const int kc = (lane >> 4) << 3;

    f32x4 acc[2] = {};
    float4 av0, av1;

    auto loadA = [&](int k0) {
        const float4* pa = (const float4*)(aSrc + k0);
        av0 = pa[0]; av1 = pa[1];
    };
    auto stageB = [&](int buf, int k0) {
#pragma unroll
        for (int i = 0; i < 2; ++i) {
            const int L = i * 4096 + t * 16;
            const int row = L >> 7;
            const int sunit = ((L >> 4) & 7) ^ (row & 7);
            gload_lds16((const char*)Bb + (size_t)row * (D_DIM * 2) + k0 * 2 + sunit * 16,
                        (char*)sB[buf] + L);
        }
    };
    auto packWriteA = [&](int buf) {
        uint4 w;
        if (tok >= 0) {
            w.x = pack2(fmaxf(av0.x, 0.f), fmaxf(av0.y, 0.f));
            w.y = pack2(fmaxf(av0.z, 0.f), fmaxf(av0.w, 0.f));
            w.z = pack2(fmaxf(av1.x, 0.f), fmaxf(av1.y, 0.f));
            w.w = pack2(fmaxf(av1.z, 0.f), fmaxf(av1.w, 0.f));
        } else {
            w = make_uint4(0, 0, 0, 0);
        }
        *(uint4*)((char*)sA[buf] + sbyte) = w;
    };

    loadA(0);
    stageB(0, 0);
    packWriteA(0);
    publish();

    for (int kt = 0; kt < 16; ++kt) {
        const int cur = kt & 1;
        if (kt < 15) {
            const int k0n = (kt + 1) << 6;
            stageB(cur ^ 1, k0n);
            loadA(k0n);
        }
#pragma unroll
        for (int kk = 0; kk < 2; ++kk) {
            const int kcol = kc + kk * 32;
            const int ra = wm + fr;
            const int rb0 = wn + fr, rb1 = wn + 16 + fr;
            bf16x8 a0 = *(const bf16x8*)&sA[cur][(ra * 64 + kcol) ^ ((ra & 7) << 3)];
            bf16x8 b0 = *(const bf16x8*)&sB[cur][(rb0 * 64 + kcol) ^ ((rb0 & 7) << 3)];
            bf16x8 b1 = *(const bf16x8*)&sB[cur][(rb1 * 64 + kcol) ^ ((rb1 & 7) << 3)];
            acc[0] = MFMA16(a0, b0, acc[0], 0, 0, 0);
            acc[1] = MFMA16(a0, b1, acc[1], 0, 0, 0);
        }
        if (kt < 15) packWriteA(cur ^ 1);
        publish();   // vmcnt(0) drains stage(kt+1), then barrier publishes
    }

    const int r0 = (lane >> 4) * 4;
    const int prow0 = rowBase + wm + r0;
#pragma unroll
    for (int n = 0; n < 2; ++n) {
        const int col = colBase + wn + n * 16 + fr;
        const float bvs = b_in[branch * S_DIM + col];
#pragma unroll
        for (int r = 0; r < 4; ++r)
            Hp[(size_t)(prow0 + r) * S_DIM + col] = f2bf(acc[n][r] + bvs);
    }
}

// ---------------------------------------------------------------------------
// K3: GEMM2  out[tok,1024] = x[tok] + Hp @ W_out[br]^T + b_out
// 64x64 tiles -> grid (16, 80) = 1280 blocks. K=256 (4 steps), 2-phase dbuf,
// both operands via gload_lds, LDS-bounce coalesced epilogue.
// ---------------------------------------------------------------------------
__global__ __launch_bounds__(256) void gemm2_kernel(
    const u16* __restrict__ Hp, const u16* __restrict__ Wo,
    const float* __restrict__ b_out, const int* __restrict__ tileBranch,
    const int* __restrict__ perm, const float* __restrict__ x,
    float* __restrict__ out) {
    const int branch = tileBranch[blockIdx.y];
    if (branch < 0) return;
    const int rowBase = blockIdx.y * BM;
    const int colBase = blockIdx.x * 64;

    __shared__ __align__(16) char smem[32768];  // sA[2]8K | sB[2]8K ; bounce 17.4K overlay
    u16* sA0 = (u16*)smem;
    u16* sA1 = (u16*)(smem + 8192);
    u16* sB0 = (u16*)(smem + 16384);
    u16* sB1 = (u16*)(smem + 24576);

    const int t = threadIdx.x;
    const u16* Ab = Hp + (size_t)rowBase * S_DIM;
    const u16* Bb = Wo + (size_t)branch * D_DIM * S_DIM + (size_t)colBase * S_DIM;

    const int lane = t & 63;
    const int wid = t >> 6;
    const int wm = (wid >> 1) * 32;
    const int wn = (wid & 1) * 32;
    const int fr = lane & 15;
    const int kc = (lane >> 4) << 3;

    f32x4 acc[2][2] = {};

    auto stage = [&](u16* dA, u16* dB, int k0) {
#pragma unroll
        for (int i = 0; i < 2; ++i) {
            const int L = i * 4096 + t * 16;
            const int row = L >> 7;
            const int sunit = ((L >> 4) & 7) ^ (row & 7);
            gload_lds16((const char*)Ab + (size_t)row * (S_DIM * 2) + k0 * 2 + sunit * 16,
                        (char*)dA + L);
        }
#pragma unroll
        for (int i = 0; i < 2; ++i) {
            const int L = i * 4096 + t * 16;
            const int row = L >> 7;
            const int sunit = ((L >> 4) & 7) ^ (row & 7);
            gload_lds16((const char*)Bb + (size_t)row * (S_DIM * 2) + k0 * 2 + sunit * 16,
                        (char*)dB + L);
        }
    };
    auto compute = [&](const u16* cA, const u16* cB) {
#pragma unroll
        for (int kk = 0; kk < 2; ++kk) {
            const int kcol = kc + kk * 32;
            const int ra0 = wm + fr, ra1 = wm + 16 + fr;
            const int rb0 = wn + fr, rb1 = wn + 16 + fr;
            bf16x8 a0 = *(const bf16x8*)&cA[(ra0 * 64 + kcol) ^ ((ra0 & 7) << 3)];
            bf16x8 a1 = *(const bf16x8*)&cA[(ra1 * 64 + kcol) ^ ((ra1 & 7) << 3)];
            bf16x8 b0 = *(const bf16x8*)&cB[(rb0 * 64 + kcol) ^ ((rb0 & 7) << 3)];
            bf16x8 b1 = *(const bf16x8*)&cB[(rb1 * 64 + kcol) ^ ((rb1 & 7) << 3)];
            acc[0][0] = MFMA16(a0, b0, acc[0][0], 0, 0, 0);
            acc[0][1] = MFMA16(a0, b1, acc[0][1], 0, 0, 0);
            acc[1][0] = MFMA16(a1, b0, acc[1][0], 0, 0, 0);
            acc[1][1] = MFMA16(a1, b1, acc[1][1], 0, 0, 0);
        }
    };

    stage(sA0, sB0, 0);
    publish();
#pragma unroll
    for (int kt = 0; kt < 4; ++kt) {
        const bool even = (kt & 1) == 0;
        u16* cA = even ? sA0 : sA1;
        u16* cB = even ? sB0 : sB1;
        u16* nA = even ? sA1 : sA0;
        u16* nB = even ? sB1 : sB0;
        if (kt < 3) stage(nA, nB, (kt + 1) << 6);
        compute(cA, cB);
        publish();   // vmcnt(0) drains gload_lds (had the MFMA phase to land) + barrier
    }

    // ---- LDS-bounce epilogue: acc -> smem[64][68] f32 -> coalesced stores
    float* bo = (float*)smem;
    const int r0 = (lane >> 4) * 4;
#pragma unroll
    for (int m = 0; m < 2; ++m)
#pragma unroll
        for (int n = 0; n < 2; ++n)
#pragma unroll
            for (int r = 0; r < 4; ++r)
                bo[(wm + m * 16 + r0 + r) * 68 + wn + n * 16 + fr] = acc[m][n][r];
    __syncthreads();

    const int erow = t >> 2;                  // 0..63
    const int q4 = (t & 3) * 4;               // f32 col base within 16-col group
    const int tok2 = perm[rowBase + erow];
    if (tok2 >= 0) {
        const size_t gbase = (size_t)tok2 * D_DIM + colBase;
        const float* xr = x + gbase;
        float* orow = out + gbase;
        const float* br = b_out + (size_t)branch * D_DIM + colBase;
#pragma unroll
        for (int j = 0; j < 4; ++j) {
            const int c = q4 + j * 16;        // 4 lanes cover 16 consecutive f32
            float4 xv = *(const float4*)&xr[c];
            float4 bvv = *(const float4*)&br[c];
            float4 hv = *(const float4*)&bo[erow * 68 + c];
            float4 s;
            s.x = xv.x + bvv.x + hv.x;
            s.y = xv.y + bvv.y + hv.y;
            s.z = xv.z + bvv.z + hv.z;
            s.w = xv.w + bvv.w + hv.w;
            *(float4*)&orow[c] = s;
        }
    }
}

// ---------------------------------------------------------------------------
extern "C" void kernel_launch(void* const* d_in, const int* in_sizes, int n_in,
                              void* d_out, int out_size, void* d_ws, size_t ws_size,
                              hipStream_t stream) {
    const float* x     = (const float*)d_in[0];
    const int*   y     = (const int*)d_in[1];
    const float* W_in  = (const float*)d_in[2];
    const float* b_in  = (const float*)d_in[3];
    const float* W_out = (const float*)d_in[4];
    const float* b_out = (const float*)d_in[5];
    float* out = (float*)d_out;

    char* ws = (char*)d_ws;
    u16* Wi = (u16*)(ws);                        // 8 MB
    u16* Wo = (u16*)(ws + 8388608);              // 8 MB
    u16* Hp = (u16*)(ws + 16777216);             // 2.62 MB
    int* perm = (int*)(ws + 19398656);           // 5120*4
    int* tileBranch = (int*)(ws + 19419136);     // 80*4

    prep_kernel<<<4097, 256, 0, stream>>>(W_in, W_out, Wi, Wo, y, perm, tileBranch);

    gemm1_kernel<<<dim3(4, NTILES32), 256, 0, stream>>>(
        x, Wi, b_in, tileBranch, perm, Hp);

    gemm2_kernel<<<dim3(16, NTILES), 256, 0, stream>>>(
        Hp, Wo, b_out, tileBranch, perm, x, out);
}